// Round 3
// baseline (1295.255 us; speedup 1.0000x reference)
//
#include <hip/hip_runtime.h>
#include <hip/hip_bf16.h>
#include <math.h>

#define N_NODES 100000
#define N_EDGES 3200000
#define IN_DIM  512
#define HID     256

#define NB8     8          // XCD-aligned row buckets
#define ROWS_PB 12500      // rows per bucket
#define BCAP    420000     // slots per bucket region
#define CHUNK   4096       // edges per phase-1 workgroup
#define NSLICE  96         // phase-2 slices per bucket
#define WFT_S   260        // WfT LDS stride in ushorts
#define SPMM_BLOCKS 1024   // persistent: 4 blocks/CU @ (512,8) -> 32 waves/CU
#define OUT_BLOCKS  2048   // persistent: 8 blocks/CU @ 256 thr

typedef __attribute__((ext_vector_type(8))) _Float16 f16x8;
typedef __attribute__((ext_vector_type(2))) _Float16 h2v;
typedef __attribute__((ext_vector_type(4))) float f32x4;

__device__ __forceinline__ ushort f2h(float f) {
  return __builtin_bit_cast(ushort, (_Float16)f);
}
// f16 lo/hi of a uint -> f32 (folds into v_fma_mix_f32 at the consumer)
__device__ __forceinline__ float hlo(uint u) {
  return (float)__builtin_bit_cast(h2v, u).x;
}
__device__ __forceinline__ float hhi(uint u) {
  return (float)__builtin_bit_cast(h2v, u).y;
}

// ---------------------------------------------------------------------------
// K0: WfTb[j][k] = f16( (W2 @ fc1_W)^T ), bfused = b2@fc1_W + fc1_b; bcur8 init
__global__ __launch_bounds__(256) void fuse_weights(
    const float* __restrict__ W2, const float* __restrict__ fc1W,
    const float* __restrict__ b2, const float* __restrict__ fc1b,
    ushort* __restrict__ WfTb, float* __restrict__ bf,
    int* __restrict__ bcur8) {
  int tid = threadIdx.x;
  int i = blockIdx.x * 32 + (tid >> 3);   // k index 0..255
  int jg = (tid & 7) * 4;                 // j group
  float4 acc = {0.f, 0.f, 0.f, 0.f};
  for (int k = 0; k < HID; k++) {
    float w = W2[i * HID + k];
    float4 f = *(const float4*)(fc1W + k * 32 + jg);
    acc.x += w * f.x; acc.y += w * f.y; acc.z += w * f.z; acc.w += w * f.w;
  }
  WfTb[(jg + 0) * HID + i] = f2h(acc.x);
  WfTb[(jg + 1) * HID + i] = f2h(acc.y);
  WfTb[(jg + 2) * HID + i] = f2h(acc.z);
  WfTb[(jg + 3) * HID + i] = f2h(acc.w);
  if (blockIdx.x == 0 && tid < 32) {
    float s = fc1b[tid];
    for (int k = 0; k < HID; k++) s += b2[k] * fc1W[k * 32 + tid];
    bf[tid] = s;
  }
  if (blockIdx.x == 1 && tid < NB8) bcur8[tid] = tid * BCAP;
}

// ---------------------------------------------------------------------------
// K0b: W1T_f16[n][k] = f16(W1[k][n])
__global__ __launch_bounds__(256) void prep_w1t(
    const float* __restrict__ W1, ushort* __restrict__ W1T) {
  int n = blockIdx.x;
  for (int k = threadIdx.x; k < IN_DIM; k += 256)
    W1T[(size_t)n * IN_DIM + k] = f2h(W1[(size_t)k * HID + n]);
}

// ---------------------------------------------------------------------------
// K2a: per-block sums of cnt
__global__ __launch_bounds__(256) void blocksum_kernel(
    const int* __restrict__ cnt, int* __restrict__ bsum, int n) {
  int i = blockIdx.x * 256 + threadIdx.x;
  int v = (i < n) ? cnt[i] : 0;
  #pragma unroll
  for (int m = 1; m < 64; m <<= 1) v += __shfl_xor(v, m, 64);
  __shared__ int ws[4];
  if ((threadIdx.x & 63) == 0) ws[threadIdx.x >> 6] = v;
  __syncthreads();
  if (threadIdx.x == 0) bsum[blockIdx.x] = ws[0] + ws[1] + ws[2] + ws[3];
}

// K2b: exclusive scan of <=512 block sums
__global__ __launch_bounds__(512) void scanpart_kernel(
    int* __restrict__ bsum, int nb) {
  int tid = threadIdx.x, lane = tid & 63, wid = tid >> 6;
  int v = (tid < nb) ? bsum[tid] : 0;
  int x = v;
  #pragma unroll
  for (int d = 1; d < 64; d <<= 1) {
    int y = __shfl_up(x, d, 64);
    if (lane >= d) x += y;
  }
  __shared__ int ws[8];
  if (lane == 63) ws[wid] = x;
  __syncthreads();
  int woff = 0;
  for (int w = 0; w < wid; w++) woff += ws[w];
  if (tid < nb) bsum[tid] = woff + x - v;
}

// K2c: rowptr + cursor = bsum[block] + in-block exclusive scan
__global__ __launch_bounds__(256) void scanfinal_kernel(
    const int* __restrict__ cnt, const int* __restrict__ bsum,
    int* __restrict__ rowptr, int* __restrict__ cursor, int n) {
  int tid = threadIdx.x, lane = tid & 63, wid = tid >> 6;
  int i = blockIdx.x * 256 + tid;
  int v = (i < n) ? cnt[i] : 0;
  int x = v;
  #pragma unroll
  for (int d = 1; d < 64; d <<= 1) {
    int y = __shfl_up(x, d, 64);
    if (lane >= d) x += y;
  }
  __shared__ int ws[4];
  if (lane == 63) ws[wid] = x;
  __syncthreads();
  int woff = bsum[blockIdx.x];
  for (int w = 0; w < wid; w++) woff += ws[w];
  int excl = woff + x - v;
  if (i < n) { rowptr[i] = excl; cursor[i] = excl; }
  if (i == 0) rowptr[n] = N_EDGES;
}

// ---------------------------------------------------------------------------
// K3b: phase-1 — bin edges into 8 XCD-aligned buckets + histogram (fused).
// Staging record packed to 8B/edge: {rlocal(14b)|col(17b), val}.
__global__ __launch_bounds__(256) void scatter_p1(
    const int* __restrict__ rows, const int* __restrict__ cols,
    const float* __restrict__ vals, int* __restrict__ bcur8,
    int2* __restrict__ tcv, int* __restrict__ cnt, int n) {
  __shared__ int bcnt[NB8];
  __shared__ int bcur[NB8];
  int tid = threadIdx.x;
  int chunk0 = blockIdx.x * CHUNK;
  if (tid < NB8) bcnt[tid] = 0;
  __syncthreads();

  int r[16], c[16], b[16];
  float v[16];
  #pragma unroll
  for (int i = 0; i < 16; i++) {
    int idx = chunk0 + i * 256 + tid;
    if (idx < n) {
      r[i] = rows[idx];
      c[i] = cols[idx];
      v[i] = vals[idx];
      b[i] = r[i] / ROWS_PB;
      atomicAdd(&bcnt[b[i]], 1);
      atomicAdd(&cnt[r[i]], 1);          // fused histogram
    } else {
      b[i] = -1;
    }
  }
  __syncthreads();
  if (tid < NB8) bcur[tid] = atomicAdd(&bcur8[tid], bcnt[tid]);
  __syncthreads();
  #pragma unroll
  for (int i = 0; i < 16; i++) {
    if (b[i] >= 0) {
      int p = atomicAdd(&bcur[b[i]], 1);
      int rl = r[i] - b[i] * ROWS_PB;      // < 12500, fits 14 bits
      int2 e; e.x = (rl << 17) | c[i]; e.y = __float_as_int(v[i]);
      tcv[p] = e;
    }
  }
}

// K3c: phase-2 — per-bucket scatter to final CSR, bucket pinned to XCD.
__global__ __launch_bounds__(256) void scatter_p2(
    const int* __restrict__ bcur8, const int2* __restrict__ tcv,
    int* __restrict__ cursor, int2* __restrict__ cv) {
  int b = blockIdx.x & 7;
  int s = blockIdx.x >> 3;
  int base = b * BCAP;
  int rbase = b * ROWS_PB;
  int ecnt = bcur8[b] - base;
  int per = (ecnt + NSLICE - 1) / NSLICE;
  int lo = s * per;
  int hi = min(ecnt, lo + per);
  for (int i = base + lo + threadIdx.x; i < base + hi; i += 256) {
    int2 e = tcv[i];
    int rl = ((uint)e.x) >> 17;
    int p = atomicAdd(&cursor[rbase + rl], 1);
    int2 o; o.x = e.x & 0x1FFFF; o.y = e.y;
    cv[p] = o;
  }
}

// ---------------------------------------------------------------------------
// K4: S1_f16 = f16( X @ W1 )  MFMA 16x16x32 f16. BM=128 BN=256 BK=32.
// 512 threads, 8 waves (2x4), per-wave 64x64 -> acc[4][4] (64 VGPR).
__global__ __launch_bounds__(512, 4) void gemm1_mfma(
    const float* __restrict__ A, const ushort* __restrict__ BT,
    ushort* __restrict__ C, int M) {
  __shared__ __align__(16) char smem[32768];
  ushort* As = (ushort*)smem;              // [128][40]
  ushort* Bs = (ushort*)(smem + 10240);    // [256][40]
  int tid = threadIdx.x;
  int bm = blockIdx.x * 128;
  int lane = tid & 63, wid = tid >> 6;     // 8 waves
  int waveM = wid >> 2, waveN = wid & 3;   // 2 x 4
  int l16 = lane & 15, quad = lane >> 4;

  f32x4 acc[4][4] = {};

  int ar = tid >> 2;                       // 0..127
  int ac = (tid & 3) * 8;                  // 0,8,16,24
  const float* aptr = A + (size_t)(bm + ar) * IN_DIM + ac;
  bool avalid = (bm + ar) < M;
  ushort* aw = As + ar * 40 + ac;
  int br = tid >> 1;                       // 0..255
  int bc = (tid & 1) * 16;
  const ushort* bptr = BT + (size_t)br * IN_DIM + bc;
  ushort* bw = Bs + br * 40 + bc;

  for (int k0 = 0; k0 < IN_DIM; k0 += 32) {
    #pragma unroll
    for (int i = 0; i < 2; i++) {
      float4 av = {0.f, 0.f, 0.f, 0.f};
      if (avalid) av = *(const float4*)(aptr + k0 + i * 4);
      ushort4 p;
      p.x = f2h(av.x); p.y = f2h(av.y); p.z = f2h(av.z); p.w = f2h(av.w);
      *(ushort4*)(aw + i * 4) = p;
    }
    *(int4*)bw = *(const int4*)(bptr + k0);
    *(int4*)(bw + 8) = *(const int4*)(bptr + k0 + 8);
    __syncthreads();

    f16x8 af[4], bfv[4];
    #pragma unroll
    for (int mi = 0; mi < 4; mi++)
      af[mi] = *(const f16x8*)(As + (waveM * 64 + mi * 16 + l16) * 40 + quad * 8);
    #pragma unroll
    for (int ni = 0; ni < 4; ni++)
      bfv[ni] = *(const f16x8*)(Bs + (waveN * 64 + ni * 16 + l16) * 40 + quad * 8);
    #pragma unroll
    for (int mi = 0; mi < 4; mi++)
      #pragma unroll
      for (int ni = 0; ni < 4; ni++)
        acc[mi][ni] = __builtin_amdgcn_mfma_f32_16x16x32_f16(
            af[mi], bfv[ni], acc[mi][ni], 0, 0, 0);
    __syncthreads();
  }

  // 2-pass epilogue through 32KB LDS (64 rows at a time)
  ushort* Cs = (ushort*)smem;              // [64][256]
  #pragma unroll
  for (int wm = 0; wm < 2; wm++) {
    if (waveM == wm) {
      #pragma unroll
      for (int mi = 0; mi < 4; mi++)
        #pragma unroll
        for (int ni = 0; ni < 4; ni++)
          #pragma unroll
          for (int r = 0; r < 4; r++)
            Cs[(mi * 16 + quad * 4 + r) * 256 + waveN * 64 + ni * 16 + l16] =
                f2h(acc[mi][ni][r]);
    }
    __syncthreads();
    int rbase = bm + wm * 64;
    #pragma unroll
    for (int i = 0; i < 4; i++) {
      int f = tid + i * 512;               // 2048 int4 total
      int r = f >> 5, v8 = f & 31;
      if (rbase + r < M)
        *(int4*)(C + (size_t)(rbase + r) * HID + v8 * 8) =
            *(const int4*)(Cs + r * 256 + v8 * 8);
    }
    __syncthreads();
  }
}

// ---------------------------------------------------------------------------
// K5: fused: h = relu(A_sp @ S1 + b1) in LDS (fp32); S2_f16 = h @ Wf.
// PERSISTENT blocks over CONTIGUOUS row chunks (load balance, locality).
// 8-edge unroll, (512,8): fits 64-VGPR cap, no scratch (R2 lesson).
__global__ __launch_bounds__(512, 8) void spmm_fused(
    const int* __restrict__ rowptr, const int2* __restrict__ cv,
    const ushort* __restrict__ S, const float* __restrict__ bias,
    const ushort* __restrict__ WfTb, ushort* __restrict__ S2b,
    int nrows, int rpb) {
  __shared__ ushort WfT[32 * WFT_S];   // 16.25 KB f16, [j][k]
  __shared__ float hbuf[8][256];       // 8 KB
  int tid = threadIdx.x;
  for (int idx = tid; idx < 32 * 64; idx += 512) {
    int jj = idx >> 6, kg = idx & 63;
    *(ushort4*)&WfT[jj * WFT_S + kg * 4] = *(const ushort4*)&WfTb[jj * HID + kg * 4];
  }
  __syncthreads();

  int w = tid >> 6, lane = tid & 63;
  int jo = lane & 31;
  int kbase = (lane >> 5) * 128;
  const float* hb = &hbuf[w][kbase];
  const ushort* wt = &WfT[jo * WFT_S + kbase];
  const ushort* Sl = S + lane * 4;
  float4 b = *(const float4*)(bias + lane * 4);

  int lo = blockIdx.x * rpb;
  int hi = min(nrows, lo + rpb);

  for (int row = lo + w; row < hi; row += 8) {
    int start = rowptr[row], end = rowptr[row + 1];
    float A0 = 0.f, A1 = 0.f, A2 = 0.f, A3 = 0.f;
    int j = start;
    if ((j & 1) && j < end) {            // align j to even for int4 cv loads
      int2 e0 = cv[j];
      float v0 = __int_as_float(e0.y);
      uint2 u0 = *(const uint2*)(Sl + (size_t)e0.x * HID);
      A0 += v0 * hlo(u0.x); A1 += v0 * hhi(u0.x);
      A2 += v0 * hlo(u0.y); A3 += v0 * hhi(u0.y);
      j++;
    }
    for (; j + 7 < end; j += 8) {
      int4 E[4];
      #pragma unroll
      for (int t = 0; t < 4; t++)
        E[t] = *(const int4*)((const int*)(cv + j) + t * 4);
      uint2 u[8];
      #pragma unroll
      for (int t = 0; t < 4; t++) {
        u[2 * t]     = *(const uint2*)(Sl + (size_t)E[t].x * HID);
        u[2 * t + 1] = *(const uint2*)(Sl + (size_t)E[t].z * HID);
      }
      #pragma unroll
      for (int t = 0; t < 4; t++) {
        float va = __int_as_float(E[t].y);
        float vb = __int_as_float(E[t].w);
        A0 += va * hlo(u[2 * t].x);     A1 += va * hhi(u[2 * t].x);
        A2 += va * hlo(u[2 * t].y);     A3 += va * hhi(u[2 * t].y);
        A0 += vb * hlo(u[2 * t + 1].x); A1 += vb * hhi(u[2 * t + 1].x);
        A2 += vb * hlo(u[2 * t + 1].y); A3 += vb * hhi(u[2 * t + 1].y);
      }
    }
    for (; j + 1 < end; j += 2) {
      int4 E = *(const int4*)(cv + j);
      uint2 ua = *(const uint2*)(Sl + (size_t)E.x * HID);
      uint2 ub = *(const uint2*)(Sl + (size_t)E.z * HID);
      float va = __int_as_float(E.y), vb = __int_as_float(E.w);
      A0 += va * hlo(ua.x); A1 += va * hhi(ua.x);
      A2 += va * hlo(ua.y); A3 += va * hhi(ua.y);
      A0 += vb * hlo(ub.x); A1 += vb * hhi(ub.x);
      A2 += vb * hlo(ub.y); A3 += vb * hhi(ub.y);
    }
    if (j < end) {
      int2 e0 = cv[j];
      float v0 = __int_as_float(e0.y);
      uint2 u0 = *(const uint2*)(Sl + (size_t)e0.x * HID);
      A0 += v0 * hlo(u0.x); A1 += v0 * hhi(u0.x);
      A2 += v0 * hlo(u0.y); A3 += v0 * hhi(u0.y);
    }
    float4 h;
    h.x = fmaxf(A0 + b.x, 0.f);
    h.y = fmaxf(A1 + b.y, 0.f);
    h.z = fmaxf(A2 + b.z, 0.f);
    h.w = fmaxf(A3 + b.w, 0.f);
    *(float4*)(&hbuf[w][lane * 4]) = h;
    // same-wave producer->consumer; DS ops complete in order per wave

    float c0 = 0.f, c1 = 0.f, c2 = 0.f, c3 = 0.f;
    #pragma unroll
    for (int kk = 0; kk < 32; kk++) {
      float4 hv = *(const float4*)(hb + kk * 4);       // broadcast (free)
      uint2 wv = *(const uint2*)(wt + kk * 4);         // b64, <=2-way
      c0 += hv.x * hlo(wv.x); c1 += hv.y * hhi(wv.x);
      c2 += hv.z * hlo(wv.y); c3 += hv.w * hhi(wv.y);
    }
    float acc = (c0 + c1) + (c2 + c3);
    acc += __shfl_xor(acc, 32, 64);
    if (lane < 32) S2b[(size_t)row * 32 + jo] = f2h(acc);
  }
}

// ---------------------------------------------------------------------------
// K7: t = A_sp @ S2 + bfused; out = log_softmax(relu(t) @ fc2W + fc2b)
// PERSISTENT contiguous chunks, 16-lane row groups, 16-edge unroll.
__global__ __launch_bounds__(256, 4) void spmm32_out_kernel(
    const int* __restrict__ rowptr, const int2* __restrict__ cv,
    const ushort* __restrict__ S2b, const float* __restrict__ bf,
    const float* __restrict__ fc2W, const float* __restrict__ fc2b,
    float* __restrict__ out, int nrows, int rpb) {
  int sub = threadIdx.x >> 4;          // 0..15
  int l16 = threadIdx.x & 15;
  const ushort* Sl = S2b + l16 * 2;
  int k0 = l16 * 2, k1 = l16 * 2 + 1;
  float w00 = fc2W[k0 * 2 + 0], w01 = fc2W[k0 * 2 + 1];
  float w10 = fc2W[k1 * 2 + 0], w11 = fc2W[k1 * 2 + 1];
  float bk0 = bf[k0], bk1 = bf[k1];

  int lo = blockIdx.x * rpb;
  int hi = min(nrows, lo + rpb);

  for (int row = lo + sub; row < hi; row += 16) {
    int start = rowptr[row], end = rowptr[row + 1];
    float a0 = 0.f, a1 = 0.f;          // features 2*l16, 2*l16+1
    int j = start;
    if ((j & 1) && j < end) {
      int2 e0 = cv[j];
      float v0 = __int_as_float(e0.y);
      uint u0 = *(const uint*)(Sl + (size_t)e0.x * 32);
      a0 += v0 * hlo(u0); a1 += v0 * hhi(u0);
      j++;
    }
    for (; j + 15 < end; j += 16) {
      int4 E[8];
      #pragma unroll
      for (int t = 0; t < 8; t++)
        E[t] = *(const int4*)((const int*)(cv + j) + t * 4);
      uint u[16];
      #pragma unroll
      for (int t = 0; t < 8; t++) {
        u[2 * t]     = *(const uint*)(Sl + (size_t)E[t].x * 32);
        u[2 * t + 1] = *(const uint*)(Sl + (size_t)E[t].z * 32);
      }
      #pragma unroll
      for (int t = 0; t < 8; t++) {
        float va = __int_as_float(E[t].y);
        float vb = __int_as_float(E[t].w);
        a0 += va * hlo(u[2 * t]);     a1 += va * hhi(u[2 * t]);
        a0 += vb * hlo(u[2 * t + 1]); a1 += vb * hhi(u[2 * t + 1]);
      }
    }
    for (; j + 1 < end; j += 2) {
      int4 E = *(const int4*)(cv + j);
      uint ua = *(const uint*)(Sl + (size_t)E.x * 32);
      uint ub = *(const uint*)(Sl + (size_t)E.z * 32);
      float va = __int_as_float(E.y), vb = __int_as_float(E.w);
      a0 += va * hlo(ua); a1 += va * hhi(ua);
      a0 += vb * hlo(ub); a1 += vb * hhi(ub);
    }
    if (j < end) {
      int2 e0 = cv[j];
      float v0 = __int_as_float(e0.y);
      uint u0 = *(const uint*)(Sl + (size_t)e0.x * 32);
      a0 += v0 * hlo(u0); a1 += v0 * hhi(u0);
    }
    float h0 = fmaxf(a0 + bk0, 0.f);
    float h1 = fmaxf(a1 + bk1, 0.f);
    float z0p = h0 * w00 + h1 * w10;
    float z1p = h0 * w01 + h1 * w11;
    #pragma unroll
    for (int m = 8; m >= 1; m >>= 1) {
      z0p += __shfl_xor(z0p, m, 16);
      z1p += __shfl_xor(z1p, m, 16);
    }
    if (l16 == 0) {
      float z0 = z0p + fc2b[0];
      float z1 = z1p + fc2b[1];
      float mx = fmaxf(z0, z1);
      float lse = mx + logf(expf(z0 - mx) + expf(z1 - mx));
      float2 o = {z0 - lse, z1 - lse};
      *(float2*)(out + (size_t)row * 2) = o;
    }
  }
}

// ---------------------------------------------------------------------------
extern "C" void kernel_launch(void* const* d_in, const int* in_sizes, int n_in,
                              void* d_out, int out_size, void* d_ws, size_t ws_size,
                              hipStream_t stream) {
  const float* X     = (const float*)d_in[0];
  const int*   erow  = (const int*)d_in[1];
  const int*   ecol  = (const int*)d_in[2];
  const float* eval_ = (const float*)d_in[3];
  const float* W1    = (const float*)d_in[4];
  const float* b1    = (const float*)d_in[5];
  const float* W2    = (const float*)d_in[6];
  const float* b2    = (const float*)d_in[7];
  const float* fc1W  = (const float*)d_in[8];
  const float* fc1b  = (const float*)d_in[9];
  const float* fc2W  = (const float*)d_in[10];
  const float* fc2b  = (const float*)d_in[11];
  float* out = (float*)d_out;

  size_t off = 0;
  auto alloc = [&](size_t bytes) {
    void* p = (char*)d_ws + off;
    off += (bytes + 255) & ~(size_t)255;
    return p;
  };
  ushort* WfTb   = (ushort*)alloc((size_t)HID * 32 * 2);
  float*  bf     = (float*)alloc(32 * 4);
  int*    cnt    = (int*)alloc((size_t)N_NODES * 4);
  int*    rowptr = (int*)alloc((size_t)(N_NODES + 1) * 4);
  int*    cursor = (int*)alloc((size_t)(N_NODES + 1) * 4);
  int*    bsum   = (int*)alloc((size_t)512 * 4);
  int*    bcur8  = (int*)alloc((size_t)64 * 4);
  int2*   cv     = (int2*)alloc((size_t)N_EDGES * 8);
  int2*   tcv    = (int2*)alloc((size_t)NB8 * BCAP * 8);
  ushort* W1T    = (ushort*)alloc((size_t)HID * IN_DIM * 2);
  ushort* S1b    = (ushort*)alloc((size_t)N_NODES * HID * 2);
  ushort* S2b    = (ushort*)alloc((size_t)N_NODES * 32 * 2);
  (void)ws_size; (void)n_in; (void)in_sizes; (void)out_size;

  const int NBLK = (N_NODES + 255) / 256;            // 391
  const int NCHUNK = (N_EDGES + CHUNK - 1) / CHUNK;  // 782
  const int SPMM_RPB = (N_NODES + SPMM_BLOCKS - 1) / SPMM_BLOCKS;  // 98
  const int OUT_RPB  = (N_NODES + OUT_BLOCKS - 1) / OUT_BLOCKS;    // 49

  hipMemsetAsync(cnt, 0, (size_t)N_NODES * 4, stream);

  fuse_weights<<<8, 256, 0, stream>>>(W2, fc1W, b2, fc1b, WfTb, bf, bcur8);
  prep_w1t<<<HID, 256, 0, stream>>>(W1, W1T);

  scatter_p1<<<NCHUNK, 256, 0, stream>>>(
      erow, ecol, eval_, bcur8, tcv, cnt, N_EDGES);
  blocksum_kernel<<<NBLK, 256, 0, stream>>>(cnt, bsum, N_NODES);
  scanpart_kernel<<<1, 512, 0, stream>>>(bsum, NBLK);
  scanfinal_kernel<<<NBLK, 256, 0, stream>>>(cnt, bsum, rowptr, cursor, N_NODES);
  scatter_p2<<<NB8 * NSLICE, 256, 0, stream>>>(bcur8, tcv, cursor, cv);

  gemm1_mfma<<<(N_NODES + 127) / 128, 512, 0, stream>>>(X, W1T, S1b, N_NODES);

  spmm_fused<<<SPMM_BLOCKS, 512, 0, stream>>>(
      rowptr, cv, S1b, b1, WfTb, S2b, N_NODES, SPMM_RPB);

  spmm32_out_kernel<<<OUT_BLOCKS, 256, 0, stream>>>(
      rowptr, cv, S2b, bf, fc2W, fc2b, out, N_NODES, OUT_RPB);
}

// Round 4
// 812.111 us; speedup vs baseline: 1.5949x; 1.5949x over previous
//
#include <hip/hip_runtime.h>
#include <hip/hip_bf16.h>
#include <math.h>

#define N_NODES 100000
#define N_EDGES 3200000
#define IN_DIM  512
#define HID     256

#define NBUK    1021       // fine row buckets (98 rows each)
#define ROWS_PBK 98        // rows per bucket
#define BCAPG   4096       // tcv slots per bucket (mean fill 3135, +17 sigma)
#define CHUNK   4096       // edges per phase-1 workgroup
#define WFT_S   260        // WfT LDS stride in ushorts

typedef __attribute__((ext_vector_type(8))) _Float16 f16x8;
typedef __attribute__((ext_vector_type(2))) _Float16 h2v;
typedef __attribute__((ext_vector_type(4))) float f32x4;

__device__ __forceinline__ ushort f2h(float f) {
  return __builtin_bit_cast(ushort, (_Float16)f);
}
// f16 lo/hi of a uint -> f32 (folds into v_fma_mix_f32 at the consumer)
__device__ __forceinline__ float hlo(uint u) {
  return (float)__builtin_bit_cast(h2v, u).x;
}
__device__ __forceinline__ float hhi(uint u) {
  return (float)__builtin_bit_cast(h2v, u).y;
}

// ---------------------------------------------------------------------------
// K0: WfTb[j][k] = f16( (W2 @ fc1_W)^T ), bfused = b2@fc1_W + fc1_b; gcur init
__global__ __launch_bounds__(256) void fuse_weights(
    const float* __restrict__ W2, const float* __restrict__ fc1W,
    const float* __restrict__ b2, const float* __restrict__ fc1b,
    ushort* __restrict__ WfTb, float* __restrict__ bf,
    int* __restrict__ gcur) {
  int tid = threadIdx.x;
  int i = blockIdx.x * 32 + (tid >> 3);   // k index 0..255
  int jg = (tid & 7) * 4;                 // j group
  float4 acc = {0.f, 0.f, 0.f, 0.f};
  for (int k = 0; k < HID; k++) {
    float w = W2[i * HID + k];
    float4 f = *(const float4*)(fc1W + k * 32 + jg);
    acc.x += w * f.x; acc.y += w * f.y; acc.z += w * f.z; acc.w += w * f.w;
  }
  WfTb[(jg + 0) * HID + i] = f2h(acc.x);
  WfTb[(jg + 1) * HID + i] = f2h(acc.y);
  WfTb[(jg + 2) * HID + i] = f2h(acc.z);
  WfTb[(jg + 3) * HID + i] = f2h(acc.w);
  if (blockIdx.x == 0 && tid < 32) {
    float s = fc1b[tid];
    for (int k = 0; k < HID; k++) s += b2[k] * fc1W[k * 32 + tid];
    bf[tid] = s;
  }
  int gid = blockIdx.x * 256 + tid;       // 2048 threads >= NBUK
  if (gid < NBUK) gcur[gid] = gid * BCAPG;
}

// ---------------------------------------------------------------------------
// K0b: W1T_f16[n][k] = f16(W1[k][n])
__global__ __launch_bounds__(256) void prep_w1t(
    const float* __restrict__ W1, ushort* __restrict__ W1T) {
  int n = blockIdx.x;
  for (int k = threadIdx.x; k < IN_DIM; k += 256)
    W1T[(size_t)n * IN_DIM + k] = f2h(W1[(size_t)k * HID + n]);
}

// ---------------------------------------------------------------------------
// K2a: per-block sums of cnt
__global__ __launch_bounds__(256) void blocksum_kernel(
    const int* __restrict__ cnt, int* __restrict__ bsum, int n) {
  int i = blockIdx.x * 256 + threadIdx.x;
  int v = (i < n) ? cnt[i] : 0;
  #pragma unroll
  for (int m = 1; m < 64; m <<= 1) v += __shfl_xor(v, m, 64);
  __shared__ int ws[4];
  if ((threadIdx.x & 63) == 0) ws[threadIdx.x >> 6] = v;
  __syncthreads();
  if (threadIdx.x == 0) bsum[blockIdx.x] = ws[0] + ws[1] + ws[2] + ws[3];
}

// K2b: exclusive scan of <=512 block sums
__global__ __launch_bounds__(512) void scanpart_kernel(
    int* __restrict__ bsum, int nb) {
  int tid = threadIdx.x, lane = tid & 63, wid = tid >> 6;
  int v = (tid < nb) ? bsum[tid] : 0;
  int x = v;
  #pragma unroll
  for (int d = 1; d < 64; d <<= 1) {
    int y = __shfl_up(x, d, 64);
    if (lane >= d) x += y;
  }
  __shared__ int ws[8];
  if (lane == 63) ws[wid] = x;
  __syncthreads();
  int woff = 0;
  for (int w = 0; w < wid; w++) woff += ws[w];
  if (tid < nb) bsum[tid] = woff + x - v;
}

// K2c: rowptr = bsum[block] + in-block exclusive scan
__global__ __launch_bounds__(256) void scanfinal_kernel(
    const int* __restrict__ cnt, const int* __restrict__ bsum,
    int* __restrict__ rowptr, int n) {
  int tid = threadIdx.x, lane = tid & 63, wid = tid >> 6;
  int i = blockIdx.x * 256 + tid;
  int v = (i < n) ? cnt[i] : 0;
  int x = v;
  #pragma unroll
  for (int d = 1; d < 64; d <<= 1) {
    int y = __shfl_up(x, d, 64);
    if (lane >= d) x += y;
  }
  __shared__ int ws[4];
  if (lane == 63) ws[wid] = x;
  __syncthreads();
  int woff = bsum[blockIdx.x];
  for (int w = 0; w < wid; w++) woff += ws[w];
  int excl = woff + x - v;
  if (i < n) rowptr[i] = excl;
  if (i == 0) rowptr[n] = N_EDGES;
}

// ---------------------------------------------------------------------------
// K3b: phase-1 — bin edges into 1021 fine buckets + histogram (fused).
// Staging record packed to 8B/edge: {rlocal(7b)<<17 | col(17b), val}.
__global__ __launch_bounds__(256) void scatter_p1(
    const int* __restrict__ rows, const int* __restrict__ cols,
    const float* __restrict__ vals, int* __restrict__ gcur,
    int2* __restrict__ tcv, int* __restrict__ cnt, int n) {
  __shared__ int bcnt[NBUK];
  __shared__ int bcur[NBUK];
  int tid = threadIdx.x;
  int chunk0 = blockIdx.x * CHUNK;
  for (int i = tid; i < NBUK; i += 256) bcnt[i] = 0;
  __syncthreads();

  int r[16], c[16], b[16];
  float v[16];
  #pragma unroll
  for (int i = 0; i < 16; i++) {
    int idx = chunk0 + i * 256 + tid;
    if (idx < n) {
      r[i] = rows[idx];
      c[i] = cols[idx];
      v[i] = vals[idx];
      b[i] = r[i] / ROWS_PBK;
      atomicAdd(&bcnt[b[i]], 1);
      atomicAdd(&cnt[r[i]], 1);          // fused histogram
    } else {
      b[i] = -1;
    }
  }
  __syncthreads();
  for (int i = tid; i < NBUK; i += 256)
    if (bcnt[i] > 0) bcur[i] = atomicAdd(&gcur[i], bcnt[i]);
  __syncthreads();
  #pragma unroll
  for (int i = 0; i < 16; i++) {
    if (b[i] >= 0) {
      int p = atomicAdd(&bcur[b[i]], 1);
      int rl = r[i] - b[i] * ROWS_PBK;     // < 98, fits 7 bits
      int2 e; e.x = (rl << 17) | c[i]; e.y = __float_as_int(v[i]);
      tcv[p] = e;
    }
  }
}

// K3c: phase-2 — per-bucket LDS-staged scatter to final CSR.
// All random writes land in LDS; global side is pure streaming.
__global__ __launch_bounds__(256) void scatter_p2(
    const int* __restrict__ rowptr, const int2* __restrict__ tcv,
    int2* __restrict__ cv) {
  __shared__ int2 buf[BCAPG];          // 32 KB
  __shared__ int lcur[ROWS_PBK];
  int b = blockIdx.x;
  int tid = threadIdx.x;
  int lo = b * ROWS_PBK;
  int hi = min(N_NODES, lo + ROWS_PBK);
  int nr = hi - lo;
  int base = rowptr[lo];
  int ecnt = rowptr[hi] - base;
  for (int r = tid; r < nr; r += 256) lcur[r] = rowptr[lo + r] - base;
  __syncthreads();
  const int2* src = tcv + (size_t)b * BCAPG;
  for (int i = tid; i < ecnt; i += 256) {
    int2 e = src[i];
    int rl = ((uint)e.x) >> 17;
    int p = atomicAdd(&lcur[rl], 1);
    int2 o; o.x = e.x & 0x1FFFF; o.y = e.y;
    buf[p] = o;
  }
  __syncthreads();
  int2* dst = cv + base;
  for (int i = tid; i < ecnt; i += 256) dst[i] = buf[i];
}

// ---------------------------------------------------------------------------
// K4: S1_f16 = f16( X @ W1 )  MFMA 16x16x32 f16. BM=128 BN=256 BK=32.
// 512 threads, 8 waves (2x4), per-wave 64x64 -> acc[4][4] (64 VGPR).
__global__ __launch_bounds__(512, 4) void gemm1_mfma(
    const float* __restrict__ A, const ushort* __restrict__ BT,
    ushort* __restrict__ C, int M) {
  __shared__ __align__(16) char smem[32768];
  ushort* As = (ushort*)smem;              // [128][40]
  ushort* Bs = (ushort*)(smem + 10240);    // [256][40]
  int tid = threadIdx.x;
  int bm = blockIdx.x * 128;
  int lane = tid & 63, wid = tid >> 6;     // 8 waves
  int waveM = wid >> 2, waveN = wid & 3;   // 2 x 4
  int l16 = lane & 15, quad = lane >> 4;

  f32x4 acc[4][4] = {};

  int ar = tid >> 2;                       // 0..127
  int ac = (tid & 3) * 8;                  // 0,8,16,24
  const float* aptr = A + (size_t)(bm + ar) * IN_DIM + ac;
  bool avalid = (bm + ar) < M;
  ushort* aw = As + ar * 40 + ac;
  int br = tid >> 1;                       // 0..255
  int bc = (tid & 1) * 16;
  const ushort* bptr = BT + (size_t)br * IN_DIM + bc;
  ushort* bw = Bs + br * 40 + bc;

  for (int k0 = 0; k0 < IN_DIM; k0 += 32) {
    #pragma unroll
    for (int i = 0; i < 2; i++) {
      float4 av = {0.f, 0.f, 0.f, 0.f};
      if (avalid) av = *(const float4*)(aptr + k0 + i * 4);
      ushort4 p;
      p.x = f2h(av.x); p.y = f2h(av.y); p.z = f2h(av.z); p.w = f2h(av.w);
      *(ushort4*)(aw + i * 4) = p;
    }
    *(int4*)bw = *(const int4*)(bptr + k0);
    *(int4*)(bw + 8) = *(const int4*)(bptr + k0 + 8);
    __syncthreads();

    f16x8 af[4], bfv[4];
    #pragma unroll
    for (int mi = 0; mi < 4; mi++)
      af[mi] = *(const f16x8*)(As + (waveM * 64 + mi * 16 + l16) * 40 + quad * 8);
    #pragma unroll
    for (int ni = 0; ni < 4; ni++)
      bfv[ni] = *(const f16x8*)(Bs + (waveN * 64 + ni * 16 + l16) * 40 + quad * 8);
    #pragma unroll
    for (int mi = 0; mi < 4; mi++)
      #pragma unroll
      for (int ni = 0; ni < 4; ni++)
        acc[mi][ni] = __builtin_amdgcn_mfma_f32_16x16x32_f16(
            af[mi], bfv[ni], acc[mi][ni], 0, 0, 0);
    __syncthreads();
  }

  // 2-pass epilogue through 32KB LDS (64 rows at a time)
  ushort* Cs = (ushort*)smem;              // [64][256]
  #pragma unroll
  for (int wm = 0; wm < 2; wm++) {
    if (waveM == wm) {
      #pragma unroll
      for (int mi = 0; mi < 4; mi++)
        #pragma unroll
        for (int ni = 0; ni < 4; ni++)
          #pragma unroll
          for (int r = 0; r < 4; r++)
            Cs[(mi * 16 + quad * 4 + r) * 256 + waveN * 64 + ni * 16 + l16] =
                f2h(acc[mi][ni][r]);
    }
    __syncthreads();
    int rbase = bm + wm * 64;
    #pragma unroll
    for (int i = 0; i < 4; i++) {
      int f = tid + i * 512;               // 2048 int4 total
      int r = f >> 5, v8 = f & 31;
      if (rbase + r < M)
        *(int4*)(C + (size_t)(rbase + r) * HID + v8 * 8) =
            *(const int4*)(Cs + r * 256 + v8 * 8);
    }
    __syncthreads();
  }
}

// ---------------------------------------------------------------------------
// K5: fused: h = relu(A_sp @ S1 + b1) in LDS (fp32); S2_f16 = h @ Wf.
// EXACT Round-0 form (896us run): 12500 blocks, 8 rows/block, 1 row/wave.
// The many-block sliding-window schedule is load-bearing for L2 gather hits
// (persistent variants: FETCH 755MB -> 1.93GB, dur 221 -> 596us. Do not).
__global__ __launch_bounds__(512, 8) void spmm_fused(
    const int* __restrict__ rowptr, const int2* __restrict__ cv,
    const ushort* __restrict__ S, const float* __restrict__ bias,
    const ushort* __restrict__ WfTb, ushort* __restrict__ S2b, int nrows) {
  __shared__ ushort WfT[32 * WFT_S];   // 16.25 KB f16, [j][k]
  __shared__ float hbuf[8][256];       // 8 KB
  int tid = threadIdx.x;
  for (int idx = tid; idx < 32 * 64; idx += 512) {
    int jj = idx >> 6, kg = idx & 63;
    *(ushort4*)&WfT[jj * WFT_S + kg * 4] = *(const ushort4*)&WfTb[jj * HID + kg * 4];
  }
  __syncthreads();

  int w = tid >> 6, lane = tid & 63;
  int row = blockIdx.x * 8 + w;
  if (row >= nrows) return;
  int start = rowptr[row], end = rowptr[row + 1];
  float A0 = 0.f, A1 = 0.f, A2 = 0.f, A3 = 0.f;
  const ushort* Sl = S + lane * 4;
  int j = start;
  if ((j & 1) && j < end) {            // align j to even for int4 cv loads
    int2 e0 = cv[j];
    float v0 = __int_as_float(e0.y);
    uint2 u0 = *(const uint2*)(Sl + (size_t)e0.x * HID);
    A0 += v0 * hlo(u0.x); A1 += v0 * hhi(u0.x);
    A2 += v0 * hlo(u0.y); A3 += v0 * hhi(u0.y);
    j++;
  }
  for (; j + 7 < end; j += 8) {
    int4 E[4];
    #pragma unroll
    for (int t = 0; t < 4; t++)
      E[t] = *(const int4*)((const int*)(cv + j) + t * 4);
    uint2 u[8];
    #pragma unroll
    for (int t = 0; t < 4; t++) {
      u[2 * t]     = *(const uint2*)(Sl + (size_t)E[t].x * HID);
      u[2 * t + 1] = *(const uint2*)(Sl + (size_t)E[t].z * HID);
    }
    #pragma unroll
    for (int t = 0; t < 4; t++) {
      float va = __int_as_float(E[t].y);
      float vb = __int_as_float(E[t].w);
      A0 += va * hlo(u[2 * t].x);     A1 += va * hhi(u[2 * t].x);
      A2 += va * hlo(u[2 * t].y);     A3 += va * hhi(u[2 * t].y);
      A0 += vb * hlo(u[2 * t + 1].x); A1 += vb * hhi(u[2 * t + 1].x);
      A2 += vb * hlo(u[2 * t + 1].y); A3 += vb * hhi(u[2 * t + 1].y);
    }
  }
  for (; j + 1 < end; j += 2) {
    int4 E = *(const int4*)(cv + j);
    uint2 ua = *(const uint2*)(Sl + (size_t)E.x * HID);
    uint2 ub = *(const uint2*)(Sl + (size_t)E.z * HID);
    float va = __int_as_float(E.y), vb = __int_as_float(E.w);
    A0 += va * hlo(ua.x); A1 += va * hhi(ua.x);
    A2 += va * hlo(ua.y); A3 += va * hhi(ua.y);
    A0 += vb * hlo(ub.x); A1 += vb * hhi(ub.x);
    A2 += vb * hlo(ub.y); A3 += vb * hhi(ub.y);
  }
  if (j < end) {
    int2 e0 = cv[j];
    float v0 = __int_as_float(e0.y);
    uint2 u0 = *(const uint2*)(Sl + (size_t)e0.x * HID);
    A0 += v0 * hlo(u0.x); A1 += v0 * hhi(u0.x);
    A2 += v0 * hlo(u0.y); A3 += v0 * hhi(u0.y);
  }
  float4 b = *(const float4*)(bias + lane * 4);
  float4 h;
  h.x = fmaxf(A0 + b.x, 0.f);
  h.y = fmaxf(A1 + b.y, 0.f);
  h.z = fmaxf(A2 + b.z, 0.f);
  h.w = fmaxf(A3 + b.w, 0.f);
  *(float4*)(&hbuf[w][lane * 4]) = h;
  // same-wave producer->consumer; compiler orders via lgkmcnt

  int jo = lane & 31;
  int kbase = (lane >> 5) * 128;
  const float* hb = &hbuf[w][kbase];
  const ushort* wt = &WfT[jo * WFT_S + kbase];
  float c0 = 0.f, c1 = 0.f, c2 = 0.f, c3 = 0.f;
  #pragma unroll
  for (int kk = 0; kk < 32; kk++) {
    float4 hv = *(const float4*)(hb + kk * 4);       // broadcast (free)
    uint2 wv = *(const uint2*)(wt + kk * 4);         // b64, <=2-way
    c0 += hv.x * hlo(wv.x); c1 += hv.y * hhi(wv.x);
    c2 += hv.z * hlo(wv.y); c3 += hv.w * hhi(wv.y);
  }
  float acc = (c0 + c1) + (c2 + c3);
  acc += __shfl_xor(acc, 32, 64);
  if (lane < 32) S2b[(size_t)row * 32 + jo] = f2h(acc);
}

// ---------------------------------------------------------------------------
// K7: t = A_sp @ S2 + bfused; out = log_softmax(relu(t) @ fc2W + fc2b)
// EXACT Round-0 form: 6250 blocks, 16-lane row groups, 16 rows/block.
__global__ __launch_bounds__(256) void spmm32_out_kernel(
    const int* __restrict__ rowptr, const int2* __restrict__ cv,
    const ushort* __restrict__ S2b, const float* __restrict__ bf,
    const float* __restrict__ fc2W, const float* __restrict__ fc2b,
    float* __restrict__ out, int nrows) {
  int sub = threadIdx.x >> 4;          // 0..15
  int l16 = threadIdx.x & 15;
  int row = blockIdx.x * 16 + sub;
  if (row >= nrows) return;
  int start = rowptr[row], end = rowptr[row + 1];
  float a0 = 0.f, a1 = 0.f;            // features 2*l16, 2*l16+1
  const ushort* Sl = S2b + l16 * 2;
  int j = start;
  if ((j & 1) && j < end) {
    int2 e0 = cv[j];
    float v0 = __int_as_float(e0.y);
    uint u0 = *(const uint*)(Sl + (size_t)e0.x * 32);
    a0 += v0 * hlo(u0); a1 += v0 * hhi(u0);
    j++;
  }
  for (; j + 15 < end; j += 16) {
    int4 E[8];
    #pragma unroll
    for (int t = 0; t < 8; t++)
      E[t] = *(const int4*)((const int*)(cv + j) + t * 4);
    uint u[16];
    #pragma unroll
    for (int t = 0; t < 8; t++) {
      u[2 * t]     = *(const uint*)(Sl + (size_t)E[t].x * 32);
      u[2 * t + 1] = *(const uint*)(Sl + (size_t)E[t].z * 32);
    }
    #pragma unroll
    for (int t = 0; t < 8; t++) {
      float va = __int_as_float(E[t].y);
      float vb = __int_as_float(E[t].w);
      a0 += va * hlo(u[2 * t]);     a1 += va * hhi(u[2 * t]);
      a0 += vb * hlo(u[2 * t + 1]); a1 += vb * hhi(u[2 * t + 1]);
    }
  }
  for (; j + 1 < end; j += 2) {
    int4 E = *(const int4*)(cv + j);
    uint ua = *(const uint*)(Sl + (size_t)E.x * 32);
    uint ub = *(const uint*)(Sl + (size_t)E.z * 32);
    float va = __int_as_float(E.y), vb = __int_as_float(E.w);
    a0 += va * hlo(ua); a1 += va * hhi(ua);
    a0 += vb * hlo(ub); a1 += vb * hhi(ub);
  }
  if (j < end) {
    int2 e0 = cv[j];
    float v0 = __int_as_float(e0.y);
    uint u0 = *(const uint*)(Sl + (size_t)e0.x * 32);
    a0 += v0 * hlo(u0); a1 += v0 * hhi(u0);
  }
  int k0 = l16 * 2, k1 = l16 * 2 + 1;
  float h0 = fmaxf(a0 + bf[k0], 0.f);
  float h1 = fmaxf(a1 + bf[k1], 0.f);
  float z0p = h0 * fc2W[k0 * 2 + 0] + h1 * fc2W[k1 * 2 + 0];
  float z1p = h0 * fc2W[k0 * 2 + 1] + h1 * fc2W[k1 * 2 + 1];
  #pragma unroll
  for (int m = 8; m >= 1; m >>= 1) {
    z0p += __shfl_xor(z0p, m, 16);
    z1p += __shfl_xor(z1p, m, 16);
  }
  if (l16 == 0) {
    float z0 = z0p + fc2b[0];
    float z1 = z1p + fc2b[1];
    float mx = fmaxf(z0, z1);
    float lse = mx + logf(expf(z0 - mx) + expf(z1 - mx));
    float2 o = {z0 - lse, z1 - lse};
    *(float2*)(out + (size_t)row * 2) = o;
  }
}

// ---------------------------------------------------------------------------
extern "C" void kernel_launch(void* const* d_in, const int* in_sizes, int n_in,
                              void* d_out, int out_size, void* d_ws, size_t ws_size,
                              hipStream_t stream) {
  const float* X     = (const float*)d_in[0];
  const int*   erow  = (const int*)d_in[1];
  const int*   ecol  = (const int*)d_in[2];
  const float* eval_ = (const float*)d_in[3];
  const float* W1    = (const float*)d_in[4];
  const float* b1    = (const float*)d_in[5];
  const float* W2    = (const float*)d_in[6];
  const float* b2    = (const float*)d_in[7];
  const float* fc1W  = (const float*)d_in[8];
  const float* fc1b  = (const float*)d_in[9];
  const float* fc2W  = (const float*)d_in[10];
  const float* fc2b  = (const float*)d_in[11];
  float* out = (float*)d_out;

  size_t off = 0;
  auto alloc = [&](size_t bytes) {
    void* p = (char*)d_ws + off;
    off += (bytes + 255) & ~(size_t)255;
    return p;
  };
  ushort* WfTb   = (ushort*)alloc((size_t)HID * 32 * 2);
  float*  bf     = (float*)alloc(32 * 4);
  int*    cnt    = (int*)alloc((size_t)N_NODES * 4);
  int*    rowptr = (int*)alloc((size_t)(N_NODES + 1) * 4);
  int*    bsum   = (int*)alloc((size_t)512 * 4);
  int*    gcur   = (int*)alloc((size_t)NBUK * 4);
  int2*   cv     = (int2*)alloc((size_t)N_EDGES * 8);
  int2*   tcv    = (int2*)alloc((size_t)NBUK * BCAPG * 8);
  ushort* W1T    = (ushort*)alloc((size_t)HID * IN_DIM * 2);
  ushort* S1b    = (ushort*)alloc((size_t)N_NODES * HID * 2);
  ushort* S2b    = (ushort*)alloc((size_t)N_NODES * 32 * 2);
  (void)ws_size; (void)n_in; (void)in_sizes; (void)out_size;

  const int NBLK = (N_NODES + 255) / 256;            // 391
  const int NCHUNK = (N_EDGES + CHUNK - 1) / CHUNK;  // 782

  hipMemsetAsync(cnt, 0, (size_t)N_NODES * 4, stream);

  fuse_weights<<<8, 256, 0, stream>>>(W2, fc1W, b2, fc1b, WfTb, bf, gcur);
  prep_w1t<<<HID, 256, 0, stream>>>(W1, W1T);

  scatter_p1<<<NCHUNK, 256, 0, stream>>>(
      erow, ecol, eval_, gcur, tcv, cnt, N_EDGES);
  blocksum_kernel<<<NBLK, 256, 0, stream>>>(cnt, bsum, N_NODES);
  scanpart_kernel<<<1, 512, 0, stream>>>(bsum, NBLK);
  scanfinal_kernel<<<NBLK, 256, 0, stream>>>(cnt, bsum, rowptr, N_NODES);
  scatter_p2<<<NBUK, 256, 0, stream>>>(rowptr, tcv, cv);

  gemm1_mfma<<<(N_NODES + 127) / 128, 512, 0, stream>>>(X, W1T, S1b, N_NODES);

  spmm_fused<<<(N_NODES + 7) / 8, 512, 0, stream>>>(
      rowptr, cv, S1b, b1, WfTb, S2b, N_NODES);

  spmm32_out_kernel<<<(N_NODES + 15) / 16, 256, 0, stream>>>(
      rowptr, cv, S2b, bf, fc2W, fc2b, out, N_NODES);
}

// Round 5
// 709.302 us; speedup vs baseline: 1.8261x; 1.1449x over previous
//
#include <hip/hip_runtime.h>
#include <hip/hip_bf16.h>
#include <math.h>

#define N_NODES 100000
#define N_EDGES 3200000
#define IN_DIM  512
#define HID     256

#define NBUK    1021       // fine row buckets (98 rows each)
#define ROWS_PBK 98        // rows per bucket
#define BCAPG   4096       // tcv slots per bucket (mean fill 3135, +17 sigma)
#define CHUNK   4096       // edges per phase-1 workgroup
#define WFT_S   260        // WfT LDS stride in ushorts
#define SPMM_HALF 50000    // spmm_fused split for profiling visibility

typedef __attribute__((ext_vector_type(8))) _Float16 f16x8;
typedef __attribute__((ext_vector_type(2))) _Float16 h2v;
typedef __attribute__((ext_vector_type(4))) float f32x4;

__device__ __forceinline__ ushort f2h(float f) {
  return __builtin_bit_cast(ushort, (_Float16)f);
}
// f16 lo/hi of a uint -> f32 (folds into v_fma_mix_f32 at the consumer)
__device__ __forceinline__ float hlo(uint u) {
  return (float)__builtin_bit_cast(h2v, u).x;
}
__device__ __forceinline__ float hhi(uint u) {
  return (float)__builtin_bit_cast(h2v, u).y;
}

// ---------------------------------------------------------------------------
// K0: WfTb[j][k] = f16( (W2 @ fc1_W)^T ), bfused = b2@fc1_W + fc1_b; gcur init
__global__ __launch_bounds__(256) void fuse_weights(
    const float* __restrict__ W2, const float* __restrict__ fc1W,
    const float* __restrict__ b2, const float* __restrict__ fc1b,
    ushort* __restrict__ WfTb, float* __restrict__ bf,
    int* __restrict__ gcur) {
  int tid = threadIdx.x;
  int i = blockIdx.x * 32 + (tid >> 3);   // k index 0..255
  int jg = (tid & 7) * 4;                 // j group
  float4 acc = {0.f, 0.f, 0.f, 0.f};
  for (int k = 0; k < HID; k++) {
    float w = W2[i * HID + k];
    float4 f = *(const float4*)(fc1W + k * 32 + jg);
    acc.x += w * f.x; acc.y += w * f.y; acc.z += w * f.z; acc.w += w * f.w;
  }
  WfTb[(jg + 0) * HID + i] = f2h(acc.x);
  WfTb[(jg + 1) * HID + i] = f2h(acc.y);
  WfTb[(jg + 2) * HID + i] = f2h(acc.z);
  WfTb[(jg + 3) * HID + i] = f2h(acc.w);
  if (blockIdx.x == 0 && tid < 32) {
    float s = fc1b[tid];
    for (int k = 0; k < HID; k++) s += b2[k] * fc1W[k * 32 + tid];
    bf[tid] = s;
  }
  int gid = blockIdx.x * 256 + tid;       // 2048 threads >= NBUK
  if (gid < NBUK) gcur[gid] = gid * BCAPG;
}

// ---------------------------------------------------------------------------
// K0b: W1T_f16[n][k] = f16(W1[k][n])
__global__ __launch_bounds__(256) void prep_w1t(
    const float* __restrict__ W1, ushort* __restrict__ W1T) {
  int n = blockIdx.x;
  for (int k = threadIdx.x; k < IN_DIM; k += 256)
    W1T[(size_t)n * IN_DIM + k] = f2h(W1[(size_t)k * HID + n]);
}

// ---------------------------------------------------------------------------
// K3b: phase-1 — bin edges into 1021 fine buckets (no global cnt atomics).
// Staging record packed to 8B/edge: {rlocal(7b)<<17 | col(17b), val}.
__global__ __launch_bounds__(256) void scatter_p1(
    const int* __restrict__ rows, const int* __restrict__ cols,
    const float* __restrict__ vals, int* __restrict__ gcur,
    int2* __restrict__ tcv, int n) {
  __shared__ int bcnt[NBUK];
  __shared__ int bcur[NBUK];
  int tid = threadIdx.x;
  int chunk0 = blockIdx.x * CHUNK;
  for (int i = tid; i < NBUK; i += 256) bcnt[i] = 0;
  __syncthreads();

  int r[16], c[16], b[16];
  float v[16];
  #pragma unroll
  for (int i = 0; i < 16; i++) {
    int idx = chunk0 + i * 256 + tid;
    if (idx < n) {
      r[i] = rows[idx];
      c[i] = cols[idx];
      v[i] = vals[idx];
      b[i] = r[i] / ROWS_PBK;
      atomicAdd(&bcnt[b[i]], 1);
    } else {
      b[i] = -1;
    }
  }
  __syncthreads();
  for (int i = tid; i < NBUK; i += 256)
    if (bcnt[i] > 0) bcur[i] = atomicAdd(&gcur[i], bcnt[i]);
  __syncthreads();
  #pragma unroll
  for (int i = 0; i < 16; i++) {
    if (b[i] >= 0) {
      int p = atomicAdd(&bcur[b[i]], 1);
      int rl = r[i] - b[i] * ROWS_PBK;     // < 98, fits 7 bits
      int2 e; e.x = (rl << 17) | c[i]; e.y = __float_as_int(v[i]);
      tcv[p] = e;
    }
  }
}

// ---------------------------------------------------------------------------
// K3s: exclusive scan of 1021 bucket counts (gcur[b] - b*BCAPG) -> bbase.
__global__ __launch_bounds__(1024) void bukscan(
    const int* __restrict__ gcur, int* __restrict__ bbase,
    int* __restrict__ rowptr) {
  int tid = threadIdx.x, lane = tid & 63, wid = tid >> 6;
  int v = (tid < NBUK) ? (gcur[tid] - tid * BCAPG) : 0;
  int x = v;
  #pragma unroll
  for (int d = 1; d < 64; d <<= 1) {
    int y = __shfl_up(x, d, 64);
    if (lane >= d) x += y;
  }
  __shared__ int ws[16];
  if (lane == 63) ws[wid] = x;
  __syncthreads();
  int woff = 0;
  for (int w = 0; w < wid; w++) woff += ws[w];
  if (tid < NBUK) bbase[tid] = woff + x - v;
  if (tid == 0) { bbase[NBUK] = N_EDGES; rowptr[N_NODES] = N_EDGES; }
}

// ---------------------------------------------------------------------------
// K3c: phase-2 — per-bucket LDS-staged scatter to final CSR.
// Computes its own per-row offsets (bucket-local) and writes rowptr.
__global__ __launch_bounds__(256) void scatter_p2(
    const int* __restrict__ bbase, const int2* __restrict__ tcv,
    int* __restrict__ rowptr, int2* __restrict__ cv) {
  __shared__ int2 buf[BCAPG];          // 32 KB
  __shared__ int rcnt[ROWS_PBK];
  __shared__ int lcur[ROWS_PBK];
  __shared__ int ws[4];
  int b = blockIdx.x;
  int tid = threadIdx.x;
  int lo = b * ROWS_PBK;
  int hi = min(N_NODES, lo + ROWS_PBK);
  int nr = hi - lo;
  int base = bbase[b];
  int ecnt = bbase[b + 1] - base;
  for (int r = tid; r < nr; r += 256) rcnt[r] = 0;
  __syncthreads();
  const int2* src = tcv + (size_t)b * BCAPG;
  for (int i = tid; i < ecnt; i += 256) {
    int2 e = src[i];
    atomicAdd(&rcnt[((uint)e.x) >> 17], 1);
  }
  __syncthreads();
  // block-wide exclusive scan of rcnt[0..nr)
  {
    int lane = tid & 63, wid = tid >> 6;
    int v = (tid < nr) ? rcnt[tid] : 0;
    int x = v;
    #pragma unroll
    for (int d = 1; d < 64; d <<= 1) {
      int y = __shfl_up(x, d, 64);
      if (lane >= d) x += y;
    }
    if (lane == 63) ws[wid] = x;
    __syncthreads();
    int woff = 0;
    for (int w = 0; w < wid; w++) woff += ws[w];
    if (tid < nr) {
      int excl = woff + x - v;
      lcur[tid] = excl;
      rowptr[lo + tid] = base + excl;
    }
  }
  __syncthreads();
  for (int i = tid; i < ecnt; i += 256) {
    int2 e = src[i];            // L2-hot second read
    int rl = ((uint)e.x) >> 17;
    int p = atomicAdd(&lcur[rl], 1);
    int2 o; o.x = e.x & 0x1FFFF; o.y = e.y;
    buf[p] = o;
  }
  __syncthreads();
  int2* dst = cv + base;
  for (int i = tid; i < ecnt; i += 256) dst[i] = buf[i];
}

// ---------------------------------------------------------------------------
// K4: S1_f16 = f16( X @ W1 )  MFMA 16x16x32 f16. BM=128 BN=256 BK=32.
// 512 threads, 8 waves (2x4), per-wave 64x64 -> acc[4][4] (64 VGPR).
__global__ __launch_bounds__(512, 4) void gemm1_mfma(
    const float* __restrict__ A, const ushort* __restrict__ BT,
    ushort* __restrict__ C, int M) {
  __shared__ __align__(16) char smem[32768];
  ushort* As = (ushort*)smem;              // [128][40]
  ushort* Bs = (ushort*)(smem + 10240);    // [256][40]
  int tid = threadIdx.x;
  int bm = blockIdx.x * 128;
  int lane = tid & 63, wid = tid >> 6;     // 8 waves
  int waveM = wid >> 2, waveN = wid & 3;   // 2 x 4
  int l16 = lane & 15, quad = lane >> 4;

  f32x4 acc[4][4] = {};

  int ar = tid >> 2;                       // 0..127
  int ac = (tid & 3) * 8;                  // 0,8,16,24
  const float* aptr = A + (size_t)(bm + ar) * IN_DIM + ac;
  bool avalid = (bm + ar) < M;
  ushort* aw = As + ar * 40 + ac;
  int br = tid >> 1;                       // 0..255
  int bc = (tid & 1) * 16;
  const ushort* bptr = BT + (size_t)br * IN_DIM + bc;
  ushort* bw = Bs + br * 40 + bc;

  for (int k0 = 0; k0 < IN_DIM; k0 += 32) {
    #pragma unroll
    for (int i = 0; i < 2; i++) {
      float4 av = {0.f, 0.f, 0.f, 0.f};
      if (avalid) av = *(const float4*)(aptr + k0 + i * 4);
      ushort4 p;
      p.x = f2h(av.x); p.y = f2h(av.y); p.z = f2h(av.z); p.w = f2h(av.w);
      *(ushort4*)(aw + i * 4) = p;
    }
    *(int4*)bw = *(const int4*)(bptr + k0);
    *(int4*)(bw + 8) = *(const int4*)(bptr + k0 + 8);
    __syncthreads();

    f16x8 af[4], bfv[4];
    #pragma unroll
    for (int mi = 0; mi < 4; mi++)
      af[mi] = *(const f16x8*)(As + (waveM * 64 + mi * 16 + l16) * 40 + quad * 8);
    #pragma unroll
    for (int ni = 0; ni < 4; ni++)
      bfv[ni] = *(const f16x8*)(Bs + (waveN * 64 + ni * 16 + l16) * 40 + quad * 8);
    #pragma unroll
    for (int mi = 0; mi < 4; mi++)
      #pragma unroll
      for (int ni = 0; ni < 4; ni++)
        acc[mi][ni] = __builtin_amdgcn_mfma_f32_16x16x32_f16(
            af[mi], bfv[ni], acc[mi][ni], 0, 0, 0);
    __syncthreads();
  }

  // 2-pass epilogue through 32KB LDS (64 rows at a time)
  ushort* Cs = (ushort*)smem;              // [64][256]
  #pragma unroll
  for (int wm = 0; wm < 2; wm++) {
    if (waveM == wm) {
      #pragma unroll
      for (int mi = 0; mi < 4; mi++)
        #pragma unroll
        for (int ni = 0; ni < 4; ni++)
          #pragma unroll
          for (int r = 0; r < 4; r++)
            Cs[(mi * 16 + quad * 4 + r) * 256 + waveN * 64 + ni * 16 + l16] =
                f2h(acc[mi][ni][r]);
    }
    __syncthreads();
    int rbase = bm + wm * 64;
    #pragma unroll
    for (int i = 0; i < 4; i++) {
      int f = tid + i * 512;               // 2048 int4 total
      int r = f >> 5, v8 = f & 31;
      if (rbase + r < M)
        *(int4*)(C + (size_t)(rbase + r) * HID + v8 * 8) =
            *(const int4*)(Cs + r * 256 + v8 * 8);
    }
    __syncthreads();
  }
}

// ---------------------------------------------------------------------------
// K5: fused: h = relu(A_sp @ S1 + b1) in LDS (fp32); S2_f16 = h @ Wf.
// Round-0 schedule (many-block sliding window = load-bearing for L2 hits).
// Split into two half-dispatches for profiling visibility (row0..row1).
__global__ __launch_bounds__(512, 8) void spmm_fused(
    const int* __restrict__ rowptr, const int2* __restrict__ cv,
    const ushort* __restrict__ S, const float* __restrict__ bias,
    const ushort* __restrict__ WfTb, ushort* __restrict__ S2b,
    int row0, int row1) {
  __shared__ ushort WfT[32 * WFT_S];   // 16.25 KB f16, [j][k]
  __shared__ float hbuf[8][256];       // 8 KB
  int tid = threadIdx.x;
  for (int idx = tid; idx < 32 * 64; idx += 512) {
    int jj = idx >> 6, kg = idx & 63;
    *(ushort4*)&WfT[jj * WFT_S + kg * 4] = *(const ushort4*)&WfTb[jj * HID + kg * 4];
  }
  __syncthreads();

  int w = tid >> 6, lane = tid & 63;
  int row = row0 + blockIdx.x * 8 + w;
  if (row >= row1) return;
  int start = rowptr[row], end = rowptr[row + 1];
  float A0 = 0.f, A1 = 0.f, A2 = 0.f, A3 = 0.f;
  const ushort* Sl = S + lane * 4;
  int j = start;
  if ((j & 1) && j < end) {            // align j to even for int4 cv loads
    int2 e0 = cv[j];
    float v0 = __int_as_float(e0.y);
    uint2 u0 = *(const uint2*)(Sl + (size_t)e0.x * HID);
    A0 += v0 * hlo(u0.x); A1 += v0 * hhi(u0.x);
    A2 += v0 * hlo(u0.y); A3 += v0 * hhi(u0.y);
    j++;
  }
  for (; j + 7 < end; j += 8) {
    int4 E[4];
    #pragma unroll
    for (int t = 0; t < 4; t++)
      E[t] = *(const int4*)((const int*)(cv + j) + t * 4);
    uint2 u[8];
    #pragma unroll
    for (int t = 0; t < 4; t++) {
      u[2 * t]     = *(const uint2*)(Sl + (size_t)E[t].x * HID);
      u[2 * t + 1] = *(const uint2*)(Sl + (size_t)E[t].z * HID);
    }
    #pragma unroll
    for (int t = 0; t < 4; t++) {
      float va = __int_as_float(E[t].y);
      float vb = __int_as_float(E[t].w);
      A0 += va * hlo(u[2 * t].x);     A1 += va * hhi(u[2 * t].x);
      A2 += va * hlo(u[2 * t].y);     A3 += va * hhi(u[2 * t].y);
      A0 += vb * hlo(u[2 * t + 1].x); A1 += vb * hhi(u[2 * t + 1].x);
      A2 += vb * hlo(u[2 * t + 1].y); A3 += vb * hhi(u[2 * t + 1].y);
    }
  }
  for (; j + 1 < end; j += 2) {
    int4 E = *(const int4*)(cv + j);
    uint2 ua = *(const uint2*)(Sl + (size_t)E.x * HID);
    uint2 ub = *(const uint2*)(Sl + (size_t)E.z * HID);
    float va = __int_as_float(E.y), vb = __int_as_float(E.w);
    A0 += va * hlo(ua.x); A1 += va * hhi(ua.x);
    A2 += va * hlo(ua.y); A3 += va * hhi(ua.y);
    A0 += vb * hlo(ub.x); A1 += vb * hhi(ub.x);
    A2 += vb * hlo(ub.y); A3 += vb * hhi(ub.y);
  }
  if (j < end) {
    int2 e0 = cv[j];
    float v0 = __int_as_float(e0.y);
    uint2 u0 = *(const uint2*)(Sl + (size_t)e0.x * HID);
    A0 += v0 * hlo(u0.x); A1 += v0 * hhi(u0.x);
    A2 += v0 * hlo(u0.y); A3 += v0 * hhi(u0.y);
  }
  float4 b = *(const float4*)(bias + lane * 4);
  float4 h;
  h.x = fmaxf(A0 + b.x, 0.f);
  h.y = fmaxf(A1 + b.y, 0.f);
  h.z = fmaxf(A2 + b.z, 0.f);
  h.w = fmaxf(A3 + b.w, 0.f);
  *(float4*)(&hbuf[w][lane * 4]) = h;
  // same-wave producer->consumer; compiler orders via lgkmcnt

  int jo = lane & 31;
  int kbase = (lane >> 5) * 128;
  const float* hb = &hbuf[w][kbase];
  const ushort* wt = &WfT[jo * WFT_S + kbase];
  float c0 = 0.f, c1 = 0.f, c2 = 0.f, c3 = 0.f;
  #pragma unroll
  for (int kk = 0; kk < 32; kk++) {
    float4 hv = *(const float4*)(hb + kk * 4);       // broadcast (free)
    uint2 wv = *(const uint2*)(wt + kk * 4);         // b64, <=2-way
    c0 += hv.x * hlo(wv.x); c1 += hv.y * hhi(wv.x);
    c2 += hv.z * hlo(wv.y); c3 += hv.w * hhi(wv.y);
  }
  float acc = (c0 + c1) + (c2 + c3);
  acc += __shfl_xor(acc, 32, 64);
  if (lane < 32) S2b[(size_t)row * 32 + jo] = f2h(acc);
}

// ---------------------------------------------------------------------------
// K7: t = A_sp @ S2 + bfused; out = log_softmax(relu(t) @ fc2W + fc2b)
__global__ __launch_bounds__(256) void spmm32_out_kernel(
    const int* __restrict__ rowptr, const int2* __restrict__ cv,
    const ushort* __restrict__ S2b, const float* __restrict__ bf,
    const float* __restrict__ fc2W, const float* __restrict__ fc2b,
    float* __restrict__ out, int nrows) {
  int sub = threadIdx.x >> 4;          // 0..15
  int l16 = threadIdx.x & 15;
  int row = blockIdx.x * 16 + sub;
  if (row >= nrows) return;
  int start = rowptr[row], end = rowptr[row + 1];
  float a0 = 0.f, a1 = 0.f;            // features 2*l16, 2*l16+1
  const ushort* Sl = S2b + l16 * 2;
  int j = start;
  if ((j & 1) && j < end) {
    int2 e0 = cv[j];
    float v0 = __int_as_float(e0.y);
    uint u0 = *(const uint*)(Sl + (size_t)e0.x * 32);
    a0 += v0 * hlo(u0); a1 += v0 * hhi(u0);
    j++;
  }
  for (; j + 15 < end; j += 16) {
    int4 E[8];
    #pragma unroll
    for (int t = 0; t < 8; t++)
      E[t] = *(const int4*)((const int*)(cv + j) + t * 4);
    uint u[16];
    #pragma unroll
    for (int t = 0; t < 8; t++) {
      u[2 * t]     = *(const uint*)(Sl + (size_t)E[t].x * 32);
      u[2 * t + 1] = *(const uint*)(Sl + (size_t)E[t].z * 32);
    }
    #pragma unroll
    for (int t = 0; t < 8; t++) {
      float va = __int_as_float(E[t].y);
      float vb = __int_as_float(E[t].w);
      a0 += va * hlo(u[2 * t]);     a1 += va * hhi(u[2 * t]);
      a0 += vb * hlo(u[2 * t + 1]); a1 += vb * hhi(u[2 * t + 1]);
    }
  }
  for (; j + 1 < end; j += 2) {
    int4 E = *(const int4*)(cv + j);
    uint ua = *(const uint*)(Sl + (size_t)E.x * 32);
    uint ub = *(const uint*)(Sl + (size_t)E.z * 32);
    float va = __int_as_float(E.y), vb = __int_as_float(E.w);
    a0 += va * hlo(ua); a1 += va * hhi(ua);
    a0 += vb * hlo(ub); a1 += vb * hhi(ub);
  }
  if (j < end) {
    int2 e0 = cv[j];
    float v0 = __int_as_float(e0.y);
    uint u0 = *(const uint*)(Sl + (size_t)e0.x * 32);
    a0 += v0 * hlo(u0); a1 += v0 * hhi(u0);
  }
  int k0 = l16 * 2, k1 = l16 * 2 + 1;
  float h0 = fmaxf(a0 + bf[k0], 0.f);
  float h1 = fmaxf(a1 + bf[k1], 0.f);
  float z0p = h0 * fc2W[k0 * 2 + 0] + h1 * fc2W[k1 * 2 + 0];
  float z1p = h0 * fc2W[k0 * 2 + 1] + h1 * fc2W[k1 * 2 + 1];
  #pragma unroll
  for (int m = 8; m >= 1; m >>= 1) {
    z0p += __shfl_xor(z0p, m, 16);
    z1p += __shfl_xor(z1p, m, 16);
  }
  if (l16 == 0) {
    float z0 = z0p + fc2b[0];
    float z1 = z1p + fc2b[1];
    float mx = fmaxf(z0, z1);
    float lse = mx + logf(expf(z0 - mx) + expf(z1 - mx));
    float2 o = {z0 - lse, z1 - lse};
    *(float2*)(out + (size_t)row * 2) = o;
  }
}

// ---------------------------------------------------------------------------
extern "C" void kernel_launch(void* const* d_in, const int* in_sizes, int n_in,
                              void* d_out, int out_size, void* d_ws, size_t ws_size,
                              hipStream_t stream) {
  const float* X     = (const float*)d_in[0];
  const int*   erow  = (const int*)d_in[1];
  const int*   ecol  = (const int*)d_in[2];
  const float* eval_ = (const float*)d_in[3];
  const float* W1    = (const float*)d_in[4];
  const float* b1    = (const float*)d_in[5];
  const float* W2    = (const float*)d_in[6];
  const float* b2    = (const float*)d_in[7];
  const float* fc1W  = (const float*)d_in[8];
  const float* fc1b  = (const float*)d_in[9];
  const float* fc2W  = (const float*)d_in[10];
  const float* fc2b  = (const float*)d_in[11];
  float* out = (float*)d_out;

  size_t off = 0;
  auto alloc = [&](size_t bytes) {
    void* p = (char*)d_ws + off;
    off += (bytes + 255) & ~(size_t)255;
    return p;
  };
  ushort* WfTb   = (ushort*)alloc((size_t)HID * 32 * 2);
  float*  bf     = (float*)alloc(32 * 4);
  int*    rowptr = (int*)alloc((size_t)(N_NODES + 1) * 4);
  int*    bbase  = (int*)alloc((size_t)(NBUK + 1) * 4);
  int*    gcur   = (int*)alloc((size_t)NBUK * 4);
  int2*   cv     = (int2*)alloc((size_t)N_EDGES * 8);
  int2*   tcv    = (int2*)alloc((size_t)NBUK * BCAPG * 8);
  ushort* W1T    = (ushort*)alloc((size_t)HID * IN_DIM * 2);
  ushort* S1b    = (ushort*)alloc((size_t)N_NODES * HID * 2);
  ushort* S2b    = (ushort*)alloc((size_t)N_NODES * 32 * 2);
  (void)ws_size; (void)n_in; (void)in_sizes; (void)out_size;

  const int NCHUNK = (N_EDGES + CHUNK - 1) / CHUNK;  // 782

  fuse_weights<<<8, 256, 0, stream>>>(W2, fc1W, b2, fc1b, WfTb, bf, gcur);
  prep_w1t<<<HID, 256, 0, stream>>>(W1, W1T);

  scatter_p1<<<NCHUNK, 256, 0, stream>>>(erow, ecol, eval_, gcur, tcv, N_EDGES);
  bukscan<<<1, 1024, 0, stream>>>(gcur, bbase, rowptr);
  scatter_p2<<<NBUK, 256, 0, stream>>>(bbase, tcv, rowptr, cv);

  gemm1_mfma<<<(N_NODES + 127) / 128, 512, 0, stream>>>(X, W1T, S1b, N_NODES);

  spmm_fused<<<(SPMM_HALF + 7) / 8, 512, 0, stream>>>(
      rowptr, cv, S1b, b1, WfTb, S2b, 0, SPMM_HALF);
  spmm_fused<<<(N_NODES - SPMM_HALF + 7) / 8, 512, 0, stream>>>(
      rowptr, cv, S1b, b1, WfTb, S2b, SPMM_HALF, N_NODES);

  spmm32_out_kernel<<<(N_NODES + 15) / 16, 256, 0, stream>>>(
      rowptr, cv, S2b, bf, fc2W, fc2b, out, N_NODES);
}